// Round 1
// baseline (357.113 us; speedup 1.0000x reference)
//
#include <hip/hip_runtime.h>
#include <hip/hip_bf16.h>

#define N_NODES 50000
#define N_EDGES 800000
#define D 64

// ---------------------------------------------------------------------------
// Workspace layout (bytes):
//   [0, 12'800'000)              agg  : float[N_NODES * D]
//   [12'800'000, 13'000'000)     out_deg : int[N_NODES]
//   [13'000'000, 13'200'000)     in_deg  : int[N_NODES]
// ---------------------------------------------------------------------------
#define AGG_OFF      0
#define OUTDEG_OFF   (N_NODES * D * sizeof(float))
#define INDEG_OFF    (OUTDEG_OFF + N_NODES * sizeof(int))
#define WS_BYTES     (INDEG_OFF + N_NODES * sizeof(int))

// Count degrees: 1 thread per edge.
__global__ void degree_kernel(const int* __restrict__ src,
                              const int* __restrict__ dst,
                              int* __restrict__ out_deg,
                              int* __restrict__ in_deg) {
    int e = blockIdx.x * blockDim.x + threadIdx.x;
    if (e < N_EDGES) {
        atomicAdd(&out_deg[src[e]], 1);
        atomicAdd(&in_deg[dst[e]], 1);
    }
}

// Scatter-add normalized messages: one wave (64 lanes) per edge, lane = feature dim.
__global__ void scatter_kernel(const float* __restrict__ x,
                               const int* __restrict__ src,
                               const int* __restrict__ dst,
                               const int* __restrict__ out_deg,
                               float* __restrict__ agg) {
    int lane = threadIdx.x & 63;
    int e = blockIdx.x * (blockDim.x >> 6) + (threadIdx.x >> 6);
    if (e < N_EDGES) {
        int s = src[e];
        int t = dst[e];
        float scale = rsqrtf(fmaxf((float)out_deg[s], 1.0f));
        float v = x[s * D + lane] * scale;
        atomicAdd(&agg[t * D + lane], v);
    }
}

// out[n][j] = rsqrt(max(in_deg[n],1)) * sum_k agg[n][k] * W[k][j] + b[j]
// Block = 256 threads = 4 nodes x 64 output columns. W staged in LDS.
__global__ void epilogue_kernel(const float* __restrict__ agg,
                                const int* __restrict__ in_deg,
                                const float* __restrict__ W,
                                const float* __restrict__ b,
                                float* __restrict__ out) {
    __shared__ float Ws[D * D];
    __shared__ float bs[D];
    for (int i = threadIdx.x; i < D * D; i += blockDim.x) Ws[i] = W[i];
    if (threadIdx.x < D) bs[threadIdx.x] = b[threadIdx.x];
    __syncthreads();

    int j = threadIdx.x & 63;
    int n = blockIdx.x * (blockDim.x >> 6) + (threadIdx.x >> 6);
    if (n < N_NODES) {
        float scale = rsqrtf(fmaxf((float)in_deg[n], 1.0f));
        const float* arow = agg + (size_t)n * D;
        float sum = 0.0f;
#pragma unroll
        for (int k = 0; k < D; k++) {
            sum = fmaf(arow[k], Ws[k * D + j], sum);
        }
        out[n * D + j] = sum * scale + bs[j];
    }
}

extern "C" void kernel_launch(void* const* d_in, const int* in_sizes, int n_in,
                              void* d_out, int out_size, void* d_ws, size_t ws_size,
                              hipStream_t stream) {
    const float* x   = (const float*)d_in[0];
    const int*   src = (const int*)d_in[1];
    const int*   dst = (const int*)d_in[2];
    const float* W   = (const float*)d_in[3];
    const float* b   = (const float*)d_in[4];
    float* out = (float*)d_out;

    char* ws = (char*)d_ws;
    float* agg    = (float*)(ws + AGG_OFF);
    int*   outdeg = (int*)(ws + OUTDEG_OFF);
    int*   indeg  = (int*)(ws + INDEG_OFF);

    // Zero the accumulator + degree arrays (ws is poisoned 0xAA before every call).
    hipMemsetAsync(d_ws, 0, WS_BYTES, stream);

    {
        int threads = 256;
        int blocks = (N_EDGES + threads - 1) / threads;
        degree_kernel<<<blocks, threads, 0, stream>>>(src, dst, outdeg, indeg);
    }
    {
        int threads = 256;                       // 4 edges per block
        int blocks = (N_EDGES + 3) / 4;
        scatter_kernel<<<blocks, threads, 0, stream>>>(x, src, dst, outdeg, agg);
    }
    {
        int threads = 256;                       // 4 nodes per block
        int blocks = (N_NODES + 3) / 4;
        epilogue_kernel<<<blocks, threads, 0, stream>>>(agg, indeg, W, b, out);
    }
}